// Round 9
// baseline (166.300 us; speedup 1.0000x reference)
//
#include <hip/hip_runtime.h>

typedef short v8s __attribute__((ext_vector_type(8)));
typedef float v4f __attribute__((ext_vector_type(4)));
typedef unsigned short u16;

#define NPIX 1024
#define EPS 1e-5f

__device__ __forceinline__ float bf2f(u16 u){
  return __uint_as_float(((unsigned)u) << 16);
}
__device__ __forceinline__ u16 f2bf(float f){
  unsigned b = __float_as_uint(f);
  b += 0x7FFF + ((b >> 16) & 1);   // RNE
  return (u16)(b >> 16);
}
// pack two f32 -> two bf16 in one VALU op (RNE, same bits as f2bf)
__device__ __forceinline__ unsigned cvtpk(float lo, float hi){
  unsigned r;
  asm("v_cvt_pk_bf16_f32 %0, %1, %2" : "=v"(r) : "v"(lo), "v"(hi));
  return r;
}
// native v_exp_f32 (2^x), bypassing OCML's checked exp2f path
__device__ __forceinline__ float exp2n(float x){
#if __has_builtin(__builtin_amdgcn_exp2f)
  return __builtin_amdgcn_exp2f(x);
#else
  float r; asm("v_exp_f32 %0, %1" : "=v"(r) : "v"(x)); return r;
#endif
}

// ---------------------------------------------------------------------------
// GEMM+BN (round-6 verified structure: K=32 steps, single-barrier dbuf).
//   A-operand = src (m = pixel), staged [pixel][k].
//   B-operand = W   (n = o-chan), [o][k] row-major -> contiguous-k b128.
// BSRC=false: src is f32 [b][c][pix] -> transpose-gather (8 scalar f32 +
//             cvtpk) per thread per k-step.
// BSRC=true:  src is bf16 [b][pix][c] (attT) -> ONE contiguous 16B ushort8
//             load + one 16B LDS store. No gather, no cvtpk.
// D-layout: lane owns ONE o-channel x 4 consecutive pixels.
// grid: (16, Cout/64, B), block 256 (4 waves).
// ---------------------------------------------------------------------------
template<bool OUT_F32, bool BSRC>
__global__ __launch_bounds__(256) void gemm_bn(
    const void* __restrict__ srcv, const float* __restrict__ W,
    const float* __restrict__ gam, const float* __restrict__ bet,
    const float* __restrict__ mu,  const float* __restrict__ var,
    u16* __restrict__ bout, float* __restrict__ fout, int Cin, int Cout)
{
  const int n0 = blockIdx.x * 64;   // pixel tile
  const int o0 = blockIdx.y * 64;   // out-channel tile
  const int b  = blockIdx.z;
  const int tid = threadIdx.x;
  const int w = tid >> 6, lane = tid & 63, col = lane & 15, quad = lane >> 4;

  const float* srcf = (const float*)srcv;
  const u16*   srcb = (const u16*)srcv;

  __shared__ u16 Wl[2][64 * 40];   // [o][k], stride 40 (80B rows, 16B-aligned)
  __shared__ u16 Sr[2][64 * 40];   // [pixel][k]

  // one BN coefficient set per lane (its single output channel)
  const int o = o0 + w * 16 + col;
  const float inv = rsqrtf(var[o] + EPS) * gam[o];
  const float add = bet[o] - mu[o] * inv;

  v4f acc[4];
#pragma unroll
  for (int i = 0; i < 4; i++) acc[i] = (v4f){0.f, 0.f, 0.f, 0.f};

  // staging assignments
  const int so = tid >> 2, sks = (tid & 3) * 8;   // W: 64 o-rows x 4 k-slots
  const int sp = tid & 63, skg = (tid >> 6) * 8;  // src: 64 pixels x 4 k-grps

  const float* wp = W + (size_t)(o0 + so) * Cin + sks;

  // prologue: tile 0 into regs
  float4 wa = ((const float4*)wp)[0];
  float4 wb = ((const float4*)wp)[1];
  float sv[8];
  v8s svb;
  if (BSRC) {
    svb = *(const v8s*)(&srcb[((size_t)b * NPIX + n0 + sp) * Cin + skg]);
  } else {
    const float* sb = srcf + ((size_t)b * Cin) * NPIX + n0 + sp;
#pragma unroll
    for (int i = 0; i < 8; i++) sv[i] = sb[(size_t)(skg + i) * NPIX];
  }

  const int nt = Cin >> 5;
  int cur = 0;
  for (int t = 0; t < nt; ++t) {
    {   // W tile -> LDS (contiguous k, no transpose)
      uint4 pk;
      pk.x = cvtpk(wa.x, wa.y);
      pk.y = cvtpk(wa.z, wa.w);
      pk.z = cvtpk(wb.x, wb.y);
      pk.w = cvtpk(wb.z, wb.w);
      *(uint4*)(&Wl[cur][so * 40 + sks]) = pk;
    }
    if (BSRC) {   // src tile: already bf16 [pixel][k] contiguous
      *(v8s*)(&Sr[cur][sp * 40 + skg]) = svb;
    } else {      // src tile: f32 transpose-gather -> bf16
      uint4 pk;
      pk.x = cvtpk(sv[0], sv[1]);
      pk.y = cvtpk(sv[2], sv[3]);
      pk.z = cvtpk(sv[4], sv[5]);
      pk.w = cvtpk(sv[6], sv[7]);
      *(uint4*)(&Sr[cur][sp * 40 + skg]) = pk;
    }
    if (t + 1 < nt) {   // issue next tile's loads (hidden under compute)
      const float* wpn = wp + (t + 1) * 32;
      wa = ((const float4*)wpn)[0];
      wb = ((const float4*)wpn)[1];
      if (BSRC) {
        svb = *(const v8s*)(&srcb[((size_t)b * NPIX + n0 + sp) * Cin +
                                  (t + 1) * 32 + skg]);
      } else {
        const float* sbn = srcf + ((size_t)b * Cin) * NPIX + n0 + sp +
                           (size_t)((t + 1) * 32 + skg) * NPIX;
#pragma unroll
        for (int i = 0; i < 8; i++) sv[i] = sbn[(size_t)i * NPIX];
      }
    }
    __syncthreads();

    v8s bfrag = *(const v8s*)(&Wl[cur][(w * 16 + col) * 40 + quad * 8]);
#pragma unroll
    for (int mt = 0; mt < 4; mt++) {
      v8s af = *(const v8s*)(&Sr[cur][(mt * 16 + col) * 40 + quad * 8]);
      acc[mt] = __builtin_amdgcn_mfma_f32_16x16x32_bf16(af, bfrag, acc[mt], 0, 0, 0);
    }
    cur ^= 1;
  }

  // epilogue: pixel = n0 + mt*16 + quad*4 + r (contiguous in r)
  const size_t orow = (size_t)(b * Cout + o) * NPIX + n0 + quad * 4;
#pragma unroll
  for (int mt = 0; mt < 4; mt++) {
    float v0 = acc[mt][0] * inv + add;
    float v1 = acc[mt][1] * inv + add;
    float v2 = acc[mt][2] * inv + add;
    float v3 = acc[mt][3] * inv + add;
    if (OUT_F32) {
      *(float4*)(&fout[orow + mt * 16]) = make_float4(v0, v1, v2, v3);
    } else {
      uint2 pk;
      pk.x = cvtpk(v0, v1);
      pk.y = cvtpk(v2, v3);
      *(uint2*)(&bout[orow + mt * 16]) = pk;
    }
  }
}

// ---------------------------------------------------------------------------
// MFMA flash attention + FUSED depthwise-3x3+BN epilogue.
// Byte-identical to round 8 (this round is a pure buffer-placement A/B).
// grid: (16 q-tiles, 8 heads, 16 batch), block 256 (4 waves, 16 q/wave).
// ---------------------------------------------------------------------------
__global__ __launch_bounds__(256) void attn_mfma_kernel(
    const u16* __restrict__ qkv, u16* __restrict__ attT,
    const float* __restrict__ wpos,
    const float* __restrict__ g_pos, const float* __restrict__ b_pos,
    const float* __restrict__ m_pos, const float* __restrict__ v_pos)
{
  const int qt = blockIdx.x, h = blockIdx.y, b = blockIdx.z;
  const int tid = threadIdx.x, w = tid >> 6, lane = tid & 63;
  const int col = lane & 15, quad = lane >> 4;
  const u16* base = qkv + (size_t)(b * 512 + h * 64) * NPIX;

  __shared__ u16 Kt[2][64 * 24];   // [j][k] transposed, stride 24
  __shared__ u16 Vl[2][32 * 72];   // [d][j], stride 72
  __shared__ u16 Pl[4][16 * 72];   // per-wave P round-trip, [query][j]

  const int q0 = qt * 64 + w * 16;

  // Q B-fragment (loop-invariant): B[n=q=col][k=quad*8+jj], k>=16 zero.
  // Scale = SCALE * log2(e) so scores feed exp2 directly.
  v8s qf = (v8s){0, 0, 0, 0, 0, 0, 0, 0};
  if (quad < 2) {
#pragma unroll
    for (int jj = 0; jj < 8; jj++) {
      int k = quad * 8 + jj;
      qf[jj] = (short)f2bf(bf2f(base[(size_t)k * NPIX + q0 + col])
                           * 0.36067376022224085f);
    }
  }

  float lsum = 0.f;
  v4f o_acc[2];
  o_acc[0] = (v4f){0, 0, 0, 0};
  o_acc[1] = (v4f){0, 0, 0, 0};

  const int kk4 = w * 4;                         // wave w stages k rows w*4..+3
  const int vd = tid >> 3, vjs = (tid & 7) * 8;  // V staging

  // prologue: tile 0 into regs
  ushort4 kr;
  kr.x = base[(size_t)(16 + kk4 + 0) * NPIX + lane];
  kr.y = base[(size_t)(16 + kk4 + 1) * NPIX + lane];
  kr.z = base[(size_t)(16 + kk4 + 2) * NPIX + lane];
  kr.w = base[(size_t)(16 + kk4 + 3) * NPIX + lane];
  uint4 vr = *(const uint4*)(base + (size_t)(32 + vd) * NPIX + vjs);

  int cur = 0;
  for (int t = 0; t < 16; ++t) {
    *(ushort4*)(&Kt[cur][lane * 24 + kk4]) = kr;   // K transposed: Kt[j][k]
    *(uint4*)(&Vl[cur][vd * 72 + vjs]) = vr;       // V: Vl[d][j]
    if (t < 15) {   // issue next tile's loads (hidden under compute)
      const int j0n = (t + 1) * 64;
      kr.x = base[(size_t)(16 + kk4 + 0) * NPIX + j0n + lane];
      kr.y = base[(size_t)(16 + kk4 + 1) * NPIX + j0n + lane];
      kr.z = base[(size_t)(16 + kk4 + 2) * NPIX + j0n + lane];
      kr.w = base[(size_t)(16 + kk4 + 3) * NPIX + j0n + lane];
      vr = *(const uint4*)(base + (size_t)(32 + vd) * NPIX + j0n + vjs);
    }
    __syncthreads();

    // scores + exp2 + packed P-store.
    // s = mfma(K, Q): D[m=key][n=query] -> row=quad*4+r is key, col is query.
#pragma unroll
    for (int jt = 0; jt < 4; jt++) {
      v8s kf = (v8s){0, 0, 0, 0, 0, 0, 0, 0};
      if (quad < 2)
        kf = *(const v8s*)(&Kt[cur][(jt * 16 + col) * 24 + quad * 8]);
      v4f z = (v4f){0, 0, 0, 0};
      v4f s = __builtin_amdgcn_mfma_f32_16x16x32_bf16(kf, qf, z, 0, 0, 0);
      float p0 = exp2n(s[0]);
      float p1 = exp2n(s[1]);
      float p2 = exp2n(s[2]);
      float p3 = exp2n(s[3]);
      lsum += (p0 + p1) + (p2 + p3);
      uint2 pk;
      pk.x = cvtpk(p0, p1);
      pk.y = cvtpk(p2, p3);
      // Pl[q=col][j = jt*16 + quad*4 .. +3]: 8B store
      *(uint2*)(&Pl[w][col * 72 + jt * 16 + quad * 4]) = pk;
    }

    // PV: D[m=query][n=d]; pf and vf from LDS (b128 reads).
#pragma unroll
    for (int T = 0; T < 2; T++) {
      v8s pf = *(const v8s*)(&Pl[w][col * 72 + T * 32 + quad * 8]);
#pragma unroll
      for (int dt = 0; dt < 2; dt++) {
        v8s vf = *(const v8s*)(&Vl[cur][(dt * 16 + col) * 72 + T * 32 + quad * 8]);
        o_acc[dt] = __builtin_amdgcn_mfma_f32_16x16x32_bf16(pf, vf, o_acc[dt], 0, 0, 0);
      }
    }
    cur ^= 1;
  }

  // ---- epilogue -----------------------------------------------------------
  // row-sums: each lane owns query q=col; fetch sums for q=quad*4+r.
  lsum += __shfl_xor(lsum, 16);
  lsum += __shfl_xor(lsum, 32);
  float ls[4];
#pragma unroll
  for (int r = 0; r < 4; r++) ls[r] = __shfl(lsum, quad * 4 + r);

  // fused depthwise-3x3 conv + BN for this lane's 2 channels x 4 pixels.
  const int p0 = q0 + quad * 4;
  const int y  = p0 >> 5, x0 = p0 & 31;

#pragma unroll
  for (int dt = 0; dt < 2; dt++) {
    const int cl = dt * 16 + col;            // channel within head (0..31)
    const int ca = h * 32 + cl;              // global att channel (0..255)
    const u16* vrow = base + (size_t)(32 + cl) * NPIX;
    const float* w9 = wpos + ca * 9;
    const float cinv = rsqrtf(v_pos[ca] + EPS) * g_pos[ca];
    const float cadd = b_pos[ca] - m_pos[ca] * cinv;

    float cv0 = 0.f, cv1 = 0.f, cv2 = 0.f, cv3 = 0.f;
#pragma unroll
    for (int ky = 0; ky < 3; ky++) {
      const int yy = y + ky - 1;
      if (yy < 0 || yy > 31) continue;       // zero-pad rows
      const u16* rp = vrow + yy * 32 + x0;
      const float w0 = w9[ky * 3 + 0];
      const float w1 = w9[ky * 3 + 1];
      const float w2 = w9[ky * 3 + 2];
      const float tm = (x0 >= 1)      ? bf2f(rp[-1]) : 0.f;   // zero-pad cols
      const float t0 = bf2f(rp[0]);
      const float t1 = bf2f(rp[1]);
      const float t2 = bf2f(rp[2]);
      const float t3 = bf2f(rp[3]);
      const float t4 = (x0 + 4 <= 31) ? bf2f(rp[4]) : 0.f;
      cv0 += tm * w0 + t0 * w1 + t1 * w2;
      cv1 += t0 * w0 + t1 * w1 + t2 * w2;
      cv2 += t1 * w0 + t2 * w1 + t3 * w2;
      cv3 += t2 * w0 + t3 * w1 + t4 * w2;
    }

    const float o0v = o_acc[dt][0] * (1.f / ls[0]) + cv0 * cinv + cadd;
    const float o1v = o_acc[dt][1] * (1.f / ls[1]) + cv1 * cinv + cadd;
    const float o2v = o_acc[dt][2] * (1.f / ls[2]) + cv2 * cinv + cadd;
    const float o3v = o_acc[dt][3] * (1.f / ls[3]) + cv3 * cinv + cadd;

    // attT[b][pix][c] bf16: 4 scalar stores (stride 512B); 16 lanes of a
    // quad write 16 consecutive u16 -> 32B segments.
    const unsigned pa = cvtpk(o0v, o1v);
    const unsigned pb = cvtpk(o2v, o3v);
    const size_t ab = ((size_t)b * NPIX + p0) * 256 + ca;
    attT[ab          ] = (u16)pa;
    attT[ab + 256    ] = (u16)(pa >> 16);
    attT[ab + 512    ] = (u16)pb;
    attT[ab + 768    ] = (u16)(pb >> 16);
  }
}

// ---------------------------------------------------------------------------
extern "C" void kernel_launch(void* const* d_in, const int* in_sizes, int n_in,
                              void* d_out, int out_size, void* d_ws, size_t ws_size,
                              hipStream_t stream)
{
  (void)in_sizes; (void)n_in; (void)out_size;
  const float* x      = (const float*)d_in[0];
  const float* w_qkv  = (const float*)d_in[1];
  const float* g_qkv  = (const float*)d_in[2];
  const float* b_qkv  = (const float*)d_in[3];
  const float* m_qkv  = (const float*)d_in[4];
  const float* v_qkv  = (const float*)d_in[5];
  const float* w_pos  = (const float*)d_in[6];
  const float* g_pos  = (const float*)d_in[7];
  const float* b_pos  = (const float*)d_in[8];
  const float* m_pos  = (const float*)d_in[9];
  const float* v_pos  = (const float*)d_in[10];
  const float* w_proj = (const float*)d_in[11];
  const float* g_proj = (const float*)d_in[12];
  const float* b_proj = (const float*)d_in[13];
  const float* m_proj = (const float*)d_in[14];
  const float* v_proj = (const float*)d_in[15];

  // Buffer plan (round-9 experiment: do NOT clobber d_in[0]):
  //   qkv  bf16 (16,512,1024):            ws[0 .. 16.78MB)
  //   attT bf16 (16,1024,256) pix-major:  ws[16.78MB .. 25.17MB)  if ws fits,
  //     else fall back to d_in[0] (round-8 plan, harness restores x).
  const size_t qkv_elems  = (size_t)16 * 512 * NPIX;          // 8.39M u16
  const size_t attT_elems = (size_t)16 * NPIX * 256;          // 4.19M u16
  u16* qkv  = (u16*)d_ws;
  u16* attT = (ws_size >= (qkv_elems + attT_elems) * sizeof(u16))
                ? (u16*)d_ws + qkv_elems
                : (u16*)d_in[0];

  // 1. qkv = BN(x @ w_qkv^T)        [bf16 out, f32 gather src]
  gemm_bn<false, false><<<dim3(16, 8, 16), 256, 0, stream>>>(
      x, w_qkv, g_qkv, b_qkv, m_qkv, v_qkv, qkv, nullptr, 256, 512);
  // 2. attT = attention(q,k,v) + BN(depthwise3x3(v))   [fused, bf16 pix-major]
  attn_mfma_kernel<<<dim3(16, 8, 16), 256, 0, stream>>>(
      qkv, attT, w_pos, g_pos, b_pos, m_pos, v_pos);
  // 3. out = BN(attT @ w_proj^T)    [f32 out, bf16 contiguous src]
  gemm_bn<true, true><<<dim3(16, 4, 16), 256, 0, stream>>>(
      attT, w_proj, g_proj, b_proj, m_proj, v_proj, nullptr,
      (float*)d_out, 256, 256);
}

// Round 10
// 162.075 us; speedup vs baseline: 1.0261x; 1.0261x over previous
//
#include <hip/hip_runtime.h>

typedef short v8s __attribute__((ext_vector_type(8)));
typedef float v4f __attribute__((ext_vector_type(4)));
typedef unsigned short u16;

#define NPIX 1024
#define EPS 1e-5f

__device__ __forceinline__ float bf2f(u16 u){
  return __uint_as_float(((unsigned)u) << 16);
}
__device__ __forceinline__ u16 f2bf(float f){
  unsigned b = __float_as_uint(f);
  b += 0x7FFF + ((b >> 16) & 1);   // RNE
  return (u16)(b >> 16);
}
// pack two f32 -> two bf16 in one VALU op (RNE, same bits as f2bf)
__device__ __forceinline__ unsigned cvtpk(float lo, float hi){
  unsigned r;
  asm("v_cvt_pk_bf16_f32 %0, %1, %2" : "=v"(r) : "v"(lo), "v"(hi));
  return r;
}
// native v_exp_f32 (2^x), bypassing OCML's checked exp2f path
__device__ __forceinline__ float exp2n(float x){
#if __has_builtin(__builtin_amdgcn_exp2f)
  return __builtin_amdgcn_exp2f(x);
#else
  float r; asm("v_exp_f32 %0, %1" : "=v"(r) : "v"(x)); return r;
#endif
}

// ---------------------------------------------------------------------------
// GEMM+BN (round-6 verified structure: K=32 steps, single-barrier dbuf).
// Unchanged from round 9.
// ---------------------------------------------------------------------------
template<bool OUT_F32, bool BSRC>
__global__ __launch_bounds__(256) void gemm_bn(
    const void* __restrict__ srcv, const float* __restrict__ W,
    const float* __restrict__ gam, const float* __restrict__ bet,
    const float* __restrict__ mu,  const float* __restrict__ var,
    u16* __restrict__ bout, float* __restrict__ fout, int Cin, int Cout)
{
  const int n0 = blockIdx.x * 64;   // pixel tile
  const int o0 = blockIdx.y * 64;   // out-channel tile
  const int b  = blockIdx.z;
  const int tid = threadIdx.x;
  const int w = tid >> 6, lane = tid & 63, col = lane & 15, quad = lane >> 4;

  const float* srcf = (const float*)srcv;
  const u16*   srcb = (const u16*)srcv;

  __shared__ u16 Wl[2][64 * 40];   // [o][k], stride 40 (80B rows, 16B-aligned)
  __shared__ u16 Sr[2][64 * 40];   // [pixel][k]

  // one BN coefficient set per lane (its single output channel)
  const int o = o0 + w * 16 + col;
  const float inv = rsqrtf(var[o] + EPS) * gam[o];
  const float add = bet[o] - mu[o] * inv;

  v4f acc[4];
#pragma unroll
  for (int i = 0; i < 4; i++) acc[i] = (v4f){0.f, 0.f, 0.f, 0.f};

  // staging assignments
  const int so = tid >> 2, sks = (tid & 3) * 8;   // W: 64 o-rows x 4 k-slots
  const int sp = tid & 63, skg = (tid >> 6) * 8;  // src: 64 pixels x 4 k-grps

  const float* wp = W + (size_t)(o0 + so) * Cin + sks;

  // prologue: tile 0 into regs
  float4 wa = ((const float4*)wp)[0];
  float4 wb = ((const float4*)wp)[1];
  float sv[8];
  v8s svb;
  if (BSRC) {
    svb = *(const v8s*)(&srcb[((size_t)b * NPIX + n0 + sp) * Cin + skg]);
  } else {
    const float* sb = srcf + ((size_t)b * Cin) * NPIX + n0 + sp;
#pragma unroll
    for (int i = 0; i < 8; i++) sv[i] = sb[(size_t)(skg + i) * NPIX];
  }

  const int nt = Cin >> 5;
  int cur = 0;
  for (int t = 0; t < nt; ++t) {
    {   // W tile -> LDS (contiguous k, no transpose)
      uint4 pk;
      pk.x = cvtpk(wa.x, wa.y);
      pk.y = cvtpk(wa.z, wa.w);
      pk.z = cvtpk(wb.x, wb.y);
      pk.w = cvtpk(wb.z, wb.w);
      *(uint4*)(&Wl[cur][so * 40 + sks]) = pk;
    }
    if (BSRC) {   // src tile: already bf16 [pixel][k] contiguous
      *(v8s*)(&Sr[cur][sp * 40 + skg]) = svb;
    } else {      // src tile: f32 transpose-gather -> bf16
      uint4 pk;
      pk.x = cvtpk(sv[0], sv[1]);
      pk.y = cvtpk(sv[2], sv[3]);
      pk.z = cvtpk(sv[4], sv[5]);
      pk.w = cvtpk(sv[6], sv[7]);
      *(uint4*)(&Sr[cur][sp * 40 + skg]) = pk;
    }
    if (t + 1 < nt) {   // issue next tile's loads (hidden under compute)
      const float* wpn = wp + (t + 1) * 32;
      wa = ((const float4*)wpn)[0];
      wb = ((const float4*)wpn)[1];
      if (BSRC) {
        svb = *(const v8s*)(&srcb[((size_t)b * NPIX + n0 + sp) * Cin +
                                  (t + 1) * 32 + skg]);
      } else {
        const float* sbn = srcf + ((size_t)b * Cin) * NPIX + n0 + sp +
                           (size_t)((t + 1) * 32 + skg) * NPIX;
#pragma unroll
        for (int i = 0; i < 8; i++) sv[i] = sbn[(size_t)i * NPIX];
      }
    }
    __syncthreads();

    v8s bfrag = *(const v8s*)(&Wl[cur][(w * 16 + col) * 40 + quad * 8]);
#pragma unroll
    for (int mt = 0; mt < 4; mt++) {
      v8s af = *(const v8s*)(&Sr[cur][(mt * 16 + col) * 40 + quad * 8]);
      acc[mt] = __builtin_amdgcn_mfma_f32_16x16x32_bf16(af, bfrag, acc[mt], 0, 0, 0);
    }
    cur ^= 1;
  }

  // epilogue: pixel = n0 + mt*16 + quad*4 + r (contiguous in r)
  const size_t orow = (size_t)(b * Cout + o) * NPIX + n0 + quad * 4;
#pragma unroll
  for (int mt = 0; mt < 4; mt++) {
    float v0 = acc[mt][0] * inv + add;
    float v1 = acc[mt][1] * inv + add;
    float v2 = acc[mt][2] * inv + add;
    float v3 = acc[mt][3] * inv + add;
    if (OUT_F32) {
      *(float4*)(&fout[orow + mt * 16]) = make_float4(v0, v1, v2, v3);
    } else {
      uint2 pk;
      pk.x = cvtpk(v0, v1);
      pk.y = cvtpk(v2, v3);
      *(uint2*)(&bout[orow + mt * 16]) = pk;
    }
  }
}

// ---------------------------------------------------------------------------
// MFMA flash attention + FUSED depthwise-3x3+BN epilogue.
// Round-10 changes (attacking the measured 23%-of-cycles LDS conflicts):
//  1. K-ROW PERMUTATION rho(j): stage key j at Kt row
//     rho = (2(j>>5)+((j&7)>>2))*16 + ((j>>3)&3)*4 + (j&3).
//     With this ordering, the 16 P-values each lane computes in the 4 QK^T
//     MFMAs are EXACTLY its PV A-fragment: pf(T) = {pka[2T],pkb[2T],
//     pka[2T+1],pkb[2T+1]} (cvtpk dwords, in order). The P LDS round-trip
//     (4 stores + 2 b128 reads/iter) and the 9.2KB Pl buffer are deleted.
//     V ordering is untouched: pf elem jj <-> true key T*32+quad*8+jj = Vl
//     column; lsum's quad-partition of keys stays exact.
//  2. XCD locality: b=blockIdx.x, qt=blockIdx.z so the 16 q-tile blocks of
//     one (b,h) share id%8 (same XCD L2) -> K/V fetched ~once per XCD.
// grid: (16 batch, 8 heads, 16 q-tiles), block 256 (4 waves, 16 q/wave).
// ---------------------------------------------------------------------------
__global__ __launch_bounds__(256) void attn_mfma_kernel(
    const u16* __restrict__ qkv, u16* __restrict__ attT,
    const float* __restrict__ wpos,
    const float* __restrict__ g_pos, const float* __restrict__ b_pos,
    const float* __restrict__ m_pos, const float* __restrict__ v_pos)
{
  const int b = blockIdx.x, h = blockIdx.y, qt = blockIdx.z;  // XCD locality
  const int tid = threadIdx.x, w = tid >> 6, lane = tid & 63;
  const int col = lane & 15, quad = lane >> 4;
  const u16* base = qkv + (size_t)(b * 512 + h * 64) * NPIX;

  __shared__ u16 Kt[2][64 * 24];   // [rho(j)][k] permuted-transposed, stride 24
  __shared__ u16 Vl[2][32 * 72];   // [d][j], stride 72

  const int q0 = qt * 64 + w * 16;

  // Q B-fragment (loop-invariant): B[n=q=col][k=quad*8+jj], k>=16 zero.
  // Scale = SCALE * log2(e) so scores feed exp2 directly.
  v8s qf = (v8s){0, 0, 0, 0, 0, 0, 0, 0};
  if (quad < 2) {
#pragma unroll
    for (int jj = 0; jj < 8; jj++) {
      int k = quad * 8 + jj;
      qf[jj] = (short)f2bf(bf2f(base[(size_t)k * NPIX + q0 + col])
                           * 0.36067376022224085f);
    }
  }

  float lsum = 0.f;
  v4f o_acc[2];
  o_acc[0] = (v4f){0, 0, 0, 0};
  o_acc[1] = (v4f){0, 0, 0, 0};

  const int kk4 = w * 4;                         // wave w stages k rows w*4..+3
  const int vd = tid >> 3, vjs = (tid & 7) * 8;  // V staging

  // permuted Kt destination row for the key this lane stages (j = lane)
  const int rho = ((2 * (lane >> 5) + ((lane & 7) >> 2)) << 4)
                  + (((lane >> 3) & 3) << 2) + (lane & 3);

  // prologue: tile 0 into regs
  ushort4 kr;
  kr.x = base[(size_t)(16 + kk4 + 0) * NPIX + lane];
  kr.y = base[(size_t)(16 + kk4 + 1) * NPIX + lane];
  kr.z = base[(size_t)(16 + kk4 + 2) * NPIX + lane];
  kr.w = base[(size_t)(16 + kk4 + 3) * NPIX + lane];
  uint4 vr = *(const uint4*)(base + (size_t)(32 + vd) * NPIX + vjs);

  int cur = 0;
  for (int t = 0; t < 16; ++t) {
    *(ushort4*)(&Kt[cur][rho * 24 + kk4]) = kr;    // key j=lane -> row rho(j)
    *(uint4*)(&Vl[cur][vd * 72 + vjs]) = vr;       // V: Vl[d][j], true order
    if (t < 15) {   // issue next tile's loads (hidden under compute)
      const int j0n = (t + 1) * 64;
      kr.x = base[(size_t)(16 + kk4 + 0) * NPIX + j0n + lane];
      kr.y = base[(size_t)(16 + kk4 + 1) * NPIX + j0n + lane];
      kr.z = base[(size_t)(16 + kk4 + 2) * NPIX + j0n + lane];
      kr.w = base[(size_t)(16 + kk4 + 3) * NPIX + j0n + lane];
      vr = *(const uint4*)(base + (size_t)(32 + vd) * NPIX + j0n + vjs);
    }
    __syncthreads();

    // scores + exp2 + packed P kept IN REGISTERS.
    // s = mfma(K,Q): lane (quad,col) gets P[key rho^-1(jt*16+quad*4+r)][q=col]
    // = by construction the keys {quad*8+jj, 32+quad*8+jj} its PV needs.
    unsigned pka[4], pkb[4];
#pragma unroll
    for (int jt = 0; jt < 4; jt++) {
      v8s kf = (v8s){0, 0, 0, 0, 0, 0, 0, 0};
      if (quad < 2)
        kf = *(const v8s*)(&Kt[cur][(jt * 16 + col) * 24 + quad * 8]);
      v4f z = (v4f){0, 0, 0, 0};
      v4f s = __builtin_amdgcn_mfma_f32_16x16x32_bf16(kf, qf, z, 0, 0, 0);
      float p0 = exp2n(s[0]);
      float p1 = exp2n(s[1]);
      float p2 = exp2n(s[2]);
      float p3 = exp2n(s[3]);
      lsum += (p0 + p1) + (p2 + p3);
      pka[jt] = cvtpk(p0, p1);
      pkb[jt] = cvtpk(p2, p3);
    }

    // PV: D[m=query][n=d]; pf assembled from this lane's own registers.
#pragma unroll
    for (int T = 0; T < 2; T++) {
      uint4 pfu = make_uint4(pka[2 * T], pkb[2 * T],
                             pka[2 * T + 1], pkb[2 * T + 1]);
      v8s pf = *(v8s*)&pfu;
#pragma unroll
      for (int dt = 0; dt < 2; dt++) {
        v8s vf = *(const v8s*)(&Vl[cur][(dt * 16 + col) * 72 + T * 32 + quad * 8]);
        o_acc[dt] = __builtin_amdgcn_mfma_f32_16x16x32_bf16(pf, vf, o_acc[dt], 0, 0, 0);
      }
    }
    cur ^= 1;
  }

  // ---- epilogue -----------------------------------------------------------
  // row-sums: each lane owns query q=col (its 16 P-values are a key-subset);
  // cross-quad reduce completes the sum; fetch sums for q=quad*4+r.
  lsum += __shfl_xor(lsum, 16);
  lsum += __shfl_xor(lsum, 32);
  float ls[4];
#pragma unroll
  for (int r = 0; r < 4; r++) ls[r] = __shfl(lsum, quad * 4 + r);

  // fused depthwise-3x3 conv + BN for this lane's 2 channels x 4 pixels.
  const int p0 = q0 + quad * 4;
  const int y  = p0 >> 5, x0 = p0 & 31;

#pragma unroll
  for (int dt = 0; dt < 2; dt++) {
    const int cl = dt * 16 + col;            // channel within head (0..31)
    const int ca = h * 32 + cl;              // global att channel (0..255)
    const u16* vrow = base + (size_t)(32 + cl) * NPIX;
    const float* w9 = wpos + ca * 9;
    const float cinv = rsqrtf(v_pos[ca] + EPS) * g_pos[ca];
    const float cadd = b_pos[ca] - m_pos[ca] * cinv;

    float cv0 = 0.f, cv1 = 0.f, cv2 = 0.f, cv3 = 0.f;
#pragma unroll
    for (int ky = 0; ky < 3; ky++) {
      const int yy = y + ky - 1;
      if (yy < 0 || yy > 31) continue;       // zero-pad rows
      const u16* rp = vrow + yy * 32 + x0;
      const float w0 = w9[ky * 3 + 0];
      const float w1 = w9[ky * 3 + 1];
      const float w2 = w9[ky * 3 + 2];
      const float tm = (x0 >= 1)      ? bf2f(rp[-1]) : 0.f;   // zero-pad cols
      const float t0 = bf2f(rp[0]);
      const float t1 = bf2f(rp[1]);
      const float t2 = bf2f(rp[2]);
      const float t3 = bf2f(rp[3]);
      const float t4 = (x0 + 4 <= 31) ? bf2f(rp[4]) : 0.f;
      cv0 += tm * w0 + t0 * w1 + t1 * w2;
      cv1 += t0 * w0 + t1 * w1 + t2 * w2;
      cv2 += t1 * w0 + t2 * w1 + t3 * w2;
      cv3 += t2 * w0 + t3 * w1 + t4 * w2;
    }

    const float o0v = o_acc[dt][0] * (1.f / ls[0]) + cv0 * cinv + cadd;
    const float o1v = o_acc[dt][1] * (1.f / ls[1]) + cv1 * cinv + cadd;
    const float o2v = o_acc[dt][2] * (1.f / ls[2]) + cv2 * cinv + cadd;
    const float o3v = o_acc[dt][3] * (1.f / ls[3]) + cv3 * cinv + cadd;

    // attT[b][pix][c] bf16: 4 scalar stores (stride 512B); 16 lanes of a
    // quad write 16 consecutive u16 -> 32B segments.
    const unsigned pa = cvtpk(o0v, o1v);
    const unsigned pb = cvtpk(o2v, o3v);
    const size_t ab = ((size_t)b * NPIX + p0) * 256 + ca;
    attT[ab          ] = (u16)pa;
    attT[ab + 256    ] = (u16)(pa >> 16);
    attT[ab + 512    ] = (u16)pb;
    attT[ab + 768    ] = (u16)(pb >> 16);
  }
}

// ---------------------------------------------------------------------------
extern "C" void kernel_launch(void* const* d_in, const int* in_sizes, int n_in,
                              void* d_out, int out_size, void* d_ws, size_t ws_size,
                              hipStream_t stream)
{
  (void)in_sizes; (void)n_in; (void)out_size;
  const float* x      = (const float*)d_in[0];
  const float* w_qkv  = (const float*)d_in[1];
  const float* g_qkv  = (const float*)d_in[2];
  const float* b_qkv  = (const float*)d_in[3];
  const float* m_qkv  = (const float*)d_in[4];
  const float* v_qkv  = (const float*)d_in[5];
  const float* w_pos  = (const float*)d_in[6];
  const float* g_pos  = (const float*)d_in[7];
  const float* b_pos  = (const float*)d_in[8];
  const float* m_pos  = (const float*)d_in[9];
  const float* v_pos  = (const float*)d_in[10];
  const float* w_proj = (const float*)d_in[11];
  const float* g_proj = (const float*)d_in[12];
  const float* b_proj = (const float*)d_in[13];
  const float* m_proj = (const float*)d_in[14];
  const float* v_proj = (const float*)d_in[15];

  // Buffer plan:
  //   qkv  bf16 (16,512,1024):            ws[0 .. 16.78MB)
  //   attT bf16 (16,1024,256) pix-major:  ws[16.78MB ..) if it fits,
  //     else fall back to d_in[0] (harness restores x).
  const size_t qkv_elems  = (size_t)16 * 512 * NPIX;
  const size_t attT_elems = (size_t)16 * NPIX * 256;
  u16* qkv  = (u16*)d_ws;
  u16* attT = (ws_size >= (qkv_elems + attT_elems) * sizeof(u16))
                ? (u16*)d_ws + qkv_elems
                : (u16*)d_in[0];

  // 1. qkv = BN(x @ w_qkv^T)        [bf16 out, f32 gather src]
  gemm_bn<false, false><<<dim3(16, 8, 16), 256, 0, stream>>>(
      x, w_qkv, g_qkv, b_qkv, m_qkv, v_qkv, qkv, nullptr, 256, 512);
  // 2. attT = attention(q,k,v) + BN(depthwise3x3(v))   [fused, bf16 pix-major]
  attn_mfma_kernel<<<dim3(16, 8, 16), 256, 0, stream>>>(
      qkv, attT, w_pos, g_pos, b_pos, m_pos, v_pos);
  // 3. out = BN(attT @ w_proj^T)    [f32 out, bf16 contiguous src]
  gemm_bn<true, true><<<dim3(16, 4, 16), 256, 0, stream>>>(
      attT, w_proj, g_proj, b_proj, m_proj, v_proj, nullptr,
      (float*)d_out, 256, 256);
}

// Round 11
// 161.505 us; speedup vs baseline: 1.0297x; 1.0035x over previous
//
#include <hip/hip_runtime.h>

typedef short v8s __attribute__((ext_vector_type(8)));
typedef float v4f __attribute__((ext_vector_type(4)));
typedef unsigned short u16;

#define NPIX 1024
#define EPS 1e-5f

__device__ __forceinline__ float bf2f(u16 u){
  return __uint_as_float(((unsigned)u) << 16);
}
__device__ __forceinline__ u16 f2bf(float f){
  unsigned b = __float_as_uint(f);
  b += 0x7FFF + ((b >> 16) & 1);   // RNE
  return (u16)(b >> 16);
}
// pack two f32 -> two bf16 in one VALU op (RNE, same bits as f2bf)
__device__ __forceinline__ unsigned cvtpk(float lo, float hi){
  unsigned r;
  asm("v_cvt_pk_bf16_f32 %0, %1, %2" : "=v"(r) : "v"(lo), "v"(hi));
  return r;
}
// native v_exp_f32 (2^x), bypassing OCML's checked exp2f path
__device__ __forceinline__ float exp2n(float x){
#if __has_builtin(__builtin_amdgcn_exp2f)
  return __builtin_amdgcn_exp2f(x);
#else
  float r; asm("v_exp_f32 %0, %1" : "=v"(r) : "v"(x)); return r;
#endif
}

// ---------------------------------------------------------------------------
// GEMM+BN (round-6 verified structure: K=32 steps, single-barrier dbuf).
// KTR (gemm1 only): wave 1's lanes own exactly the K channels
// (o = h*64+16+col, col = k index). They write K^T[b][h][j=pixel][k] to ktr
// (plain j order; attn applies the rho permutation on the read side) and
// SKIP the qkv store (attn no longer reads qkv K rows).
// grid: (16, Cout/64, B), block 256 (4 waves).
// ---------------------------------------------------------------------------
template<bool OUT_F32, bool BSRC, bool KTR>
__global__ __launch_bounds__(256) void gemm_bn(
    const void* __restrict__ srcv, const float* __restrict__ W,
    const float* __restrict__ gam, const float* __restrict__ bet,
    const float* __restrict__ mu,  const float* __restrict__ var,
    u16* __restrict__ bout, float* __restrict__ fout,
    u16* __restrict__ ktr, int Cin, int Cout)
{
  const int n0 = blockIdx.x * 64;   // pixel tile
  const int o0 = blockIdx.y * 64;   // out-channel tile
  const int b  = blockIdx.z;
  const int tid = threadIdx.x;
  const int w = tid >> 6, lane = tid & 63, col = lane & 15, quad = lane >> 4;

  const float* srcf = (const float*)srcv;
  const u16*   srcb = (const u16*)srcv;

  __shared__ u16 Wl[2][64 * 40];   // [o][k], stride 40 (80B rows, 16B-aligned)
  __shared__ u16 Sr[2][64 * 40];   // [pixel][k]

  // one BN coefficient set per lane (its single output channel)
  const int o = o0 + w * 16 + col;
  const float inv = rsqrtf(var[o] + EPS) * gam[o];
  const float add = bet[o] - mu[o] * inv;

  v4f acc[4];
#pragma unroll
  for (int i = 0; i < 4; i++) acc[i] = (v4f){0.f, 0.f, 0.f, 0.f};

  // staging assignments
  const int so = tid >> 2, sks = (tid & 3) * 8;   // W: 64 o-rows x 4 k-slots
  const int sp = tid & 63, skg = (tid >> 6) * 8;  // src: 64 pixels x 4 k-grps

  const float* wp = W + (size_t)(o0 + so) * Cin + sks;

  // prologue: tile 0 into regs
  float4 wa = ((const float4*)wp)[0];
  float4 wb = ((const float4*)wp)[1];
  float sv[8];
  v8s svb;
  if (BSRC) {
    svb = *(const v8s*)(&srcb[((size_t)b * NPIX + n0 + sp) * Cin + skg]);
  } else {
    const float* sb = srcf + ((size_t)b * Cin) * NPIX + n0 + sp;
#pragma unroll
    for (int i = 0; i < 8; i++) sv[i] = sb[(size_t)(skg + i) * NPIX];
  }

  const int nt = Cin >> 5;
  int cur = 0;
  for (int t = 0; t < nt; ++t) {
    {   // W tile -> LDS (contiguous k, no transpose)
      uint4 pk;
      pk.x = cvtpk(wa.x, wa.y);
      pk.y = cvtpk(wa.z, wa.w);
      pk.z = cvtpk(wb.x, wb.y);
      pk.w = cvtpk(wb.z, wb.w);
      *(uint4*)(&Wl[cur][so * 40 + sks]) = pk;
    }
    if (BSRC) {   // src tile: already bf16 [pixel][k] contiguous
      *(v8s*)(&Sr[cur][sp * 40 + skg]) = svb;
    } else {      // src tile: f32 transpose-gather -> bf16
      uint4 pk;
      pk.x = cvtpk(sv[0], sv[1]);
      pk.y = cvtpk(sv[2], sv[3]);
      pk.z = cvtpk(sv[4], sv[5]);
      pk.w = cvtpk(sv[6], sv[7]);
      *(uint4*)(&Sr[cur][sp * 40 + skg]) = pk;
    }
    if (t + 1 < nt) {   // issue next tile's loads (hidden under compute)
      const float* wpn = wp + (t + 1) * 32;
      wa = ((const float4*)wpn)[0];
      wb = ((const float4*)wpn)[1];
      if (BSRC) {
        svb = *(const v8s*)(&srcb[((size_t)b * NPIX + n0 + sp) * Cin +
                                  (t + 1) * 32 + skg]);
      } else {
        const float* sbn = srcf + ((size_t)b * Cin) * NPIX + n0 + sp +
                           (size_t)((t + 1) * 32 + skg) * NPIX;
#pragma unroll
        for (int i = 0; i < 8; i++) sv[i] = sbn[(size_t)i * NPIX];
      }
    }
    __syncthreads();

    v8s bfrag = *(const v8s*)(&Wl[cur][(w * 16 + col) * 40 + quad * 8]);
#pragma unroll
    for (int mt = 0; mt < 4; mt++) {
      v8s af = *(const v8s*)(&Sr[cur][(mt * 16 + col) * 40 + quad * 8]);
      acc[mt] = __builtin_amdgcn_mfma_f32_16x16x32_bf16(af, bfrag, acc[mt], 0, 0, 0);
    }
    cur ^= 1;
  }

  // epilogue: pixel = n0 + mt*16 + quad*4 + r (contiguous in r)
  if (KTR && w == 1) {
    // K channels: write K^T[(b,h)][j][k], j = pixel, k = col. Plain j order.
    const size_t ktb = (((size_t)b * 8 + blockIdx.y) * 1024 +
                       (size_t)blockIdx.x * 64) * 16 + col;
#pragma unroll
    for (int mt = 0; mt < 4; mt++) {
      float v0 = acc[mt][0] * inv + add;
      float v1 = acc[mt][1] * inv + add;
      float v2 = acc[mt][2] * inv + add;
      float v3 = acc[mt][3] * inv + add;
      unsigned pa = cvtpk(v0, v1);
      unsigned pb = cvtpk(v2, v3);
      const size_t rb = ktb + (size_t)(mt * 16 + quad * 4) * 16;
      ktr[rb     ] = (u16)pa;
      ktr[rb + 16] = (u16)(pa >> 16);
      ktr[rb + 32] = (u16)pb;
      ktr[rb + 48] = (u16)(pb >> 16);
    }
    return;
  }
  const size_t orow = (size_t)(b * Cout + o) * NPIX + n0 + quad * 4;
#pragma unroll
  for (int mt = 0; mt < 4; mt++) {
    float v0 = acc[mt][0] * inv + add;
    float v1 = acc[mt][1] * inv + add;
    float v2 = acc[mt][2] * inv + add;
    float v3 = acc[mt][3] * inv + add;
    if (OUT_F32) {
      *(float4*)(&fout[orow + mt * 16]) = make_float4(v0, v1, v2, v3);
    } else {
      uint2 pk;
      pk.x = cvtpk(v0, v1);
      pk.y = cvtpk(v2, v3);
      *(uint2*)(&bout[orow + mt * 16]) = pk;
    }
  }
}

// ---------------------------------------------------------------------------
// MFMA flash attention + FUSED depthwise-3x3+BN epilogue.
// Round-11: K comes from the pre-transposed ktr buffer (written by gemm1).
//   - kf fragments are direct COALESCED global v8s loads (512B/jt), L2-hot,
//     double-buffered in NAMED registers (even/odd tiles) with a full tile
//     of prefetch distance. K LDS staging/reads deleted (LDS 15.4->9.2KB).
//   - rho permutation applied on the READ side via loop-invariant inverse:
//     row=jt*16+col (permuted) -> true j = a*32+b*8+c*4+d.
//   - P stays in registers (round-10 trick), V staging/PV unchanged.
// grid: (16 batch, 8 heads, 16 q-tiles), block 256 (4 waves, 16 q/wave).
// ---------------------------------------------------------------------------
__global__ __launch_bounds__(256) void attn_mfma_kernel(
    const u16* __restrict__ qkv, const u16* __restrict__ ktr,
    u16* __restrict__ attT, const float* __restrict__ wpos,
    const float* __restrict__ g_pos, const float* __restrict__ b_pos,
    const float* __restrict__ m_pos, const float* __restrict__ v_pos)
{
  const int b = blockIdx.x, h = blockIdx.y, qt = blockIdx.z;  // XCD locality
  const int tid = threadIdx.x, w = tid >> 6, lane = tid & 63;
  const int col = lane & 15, quad = lane >> 4;
  const u16* base = qkv + (size_t)(b * 512 + h * 64) * NPIX;

  __shared__ u16 Vl[2][32 * 72];   // [d][j], stride 72

  const int q0 = qt * 64 + w * 16;

  // Q B-fragment (loop-invariant): B[n=q=col][k=quad*8+jj], k>=16 zero.
  // Scale = SCALE * log2(e) so scores feed exp2 directly.
  v8s qf = (v8s){0, 0, 0, 0, 0, 0, 0, 0};
  if (quad < 2) {
#pragma unroll
    for (int jj = 0; jj < 8; jj++) {
      int k = quad * 8 + jj;
      qf[jj] = (short)f2bf(bf2f(base[(size_t)k * NPIX + q0 + col])
                           * 0.36067376022224085f);
    }
  }

  // loop-invariant kf offsets: permuted row jt*16+col -> true j (inv-rho)
  int joff[4];
#pragma unroll
  for (int jt = 0; jt < 4; jt++) {
    const int row = jt * 16 + col;
    const int r4 = row >> 4;
    const int j = (r4 >> 1) * 32 + ((row >> 2) & 3) * 8 + (r4 & 1) * 4 + (row & 3);
    joff[jt] = j * 16 + quad * 8;
  }
  const u16* ktb = ktr + (size_t)(b * 8 + h) * 1024 * 16;

  float lsum = 0.f;
  v4f o_acc[2];
  o_acc[0] = (v4f){0, 0, 0, 0};
  o_acc[1] = (v4f){0, 0, 0, 0};

  const int vd = tid >> 3, vjs = (tid & 7) * 8;  // V staging

  // named double-buffered prefetch registers (no runtime-indexed arrays)
  uint4 ka0, ka1, ka2, ka3, kb0, kb1, kb2, kb3;
  ka0 = ka1 = ka2 = ka3 = kb0 = kb1 = kb2 = kb3 = make_uint4(0, 0, 0, 0);
  uint4 va, vb;

  // prologue: tile 0 -> regs A
  va = *(const uint4*)(base + (size_t)(32 + vd) * NPIX + vjs);
  if (quad < 2) {
    ka0 = *(const uint4*)(ktb + joff[0]);
    ka1 = *(const uint4*)(ktb + joff[1]);
    ka2 = *(const uint4*)(ktb + joff[2]);
    ka3 = *(const uint4*)(ktb + joff[3]);
  }

#define QKPV(BUF, K0, K1, K2, K3)                                            \
  do {                                                                       \
    unsigned pka[4], pkb[4];                                                 \
    {                                                                        \
      const uint4 kk[4] = {K0, K1, K2, K3};                                  \
      _Pragma("unroll")                                                      \
      for (int jt = 0; jt < 4; jt++) {                                       \
        v8s kf = *(const v8s*)&kk[jt];                                       \
        v4f z = (v4f){0, 0, 0, 0};                                           \
        v4f s = __builtin_amdgcn_mfma_f32_16x16x32_bf16(kf, qf, z, 0, 0, 0); \
        float p0 = exp2n(s[0]);                                              \
        float p1 = exp2n(s[1]);                                              \
        float p2 = exp2n(s[2]);                                              \
        float p3 = exp2n(s[3]);                                              \
        lsum += (p0 + p1) + (p2 + p3);                                       \
        pka[jt] = cvtpk(p0, p1);                                             \
        pkb[jt] = cvtpk(p2, p3);                                             \
      }                                                                      \
    }                                                                        \
    _Pragma("unroll")                                                        \
    for (int T = 0; T < 2; T++) {                                            \
      uint4 pfu = make_uint4(pka[2 * T], pkb[2 * T],                         \
                             pka[2 * T + 1], pkb[2 * T + 1]);                \
      v8s pf = *(v8s*)&pfu;                                                  \
      _Pragma("unroll")                                                      \
      for (int dt = 0; dt < 2; dt++) {                                       \
        v8s vf = *(const v8s*)(&Vl[BUF][(dt * 16 + col) * 72 +               \
                                        T * 32 + quad * 8]);                 \
        o_acc[dt] =                                                          \
            __builtin_amdgcn_mfma_f32_16x16x32_bf16(pf, vf, o_acc[dt], 0, 0, 0); \
      }                                                                      \
    }                                                                        \
  } while (0)

  for (int tt = 0; tt < 16; tt += 2) {
    // ---- even tile (regs A, buf 0); prefetch tile tt+1 into regs B
    *(uint4*)(&Vl[0][vd * 72 + vjs]) = va;
    {
      const int tn = tt + 1;
      vb = *(const uint4*)(base + (size_t)(32 + vd) * NPIX + tn * 64 + vjs);
      if (quad < 2) {
        const u16* kt = ktb + tn * 1024;
        kb0 = *(const uint4*)(kt + joff[0]);
        kb1 = *(const uint4*)(kt + joff[1]);
        kb2 = *(const uint4*)(kt + joff[2]);
        kb3 = *(const uint4*)(kt + joff[3]);
      }
    }
    __syncthreads();
    QKPV(0, ka0, ka1, ka2, ka3);

    // ---- odd tile (regs B, buf 1); prefetch tile tt+2 into regs A
    *(uint4*)(&Vl[1][vd * 72 + vjs]) = vb;
    if (tt + 2 < 16) {
      const int tn = tt + 2;
      va = *(const uint4*)(base + (size_t)(32 + vd) * NPIX + tn * 64 + vjs);
      if (quad < 2) {
        const u16* kt = ktb + tn * 1024;
        ka0 = *(const uint4*)(kt + joff[0]);
        ka1 = *(const uint4*)(kt + joff[1]);
        ka2 = *(const uint4*)(kt + joff[2]);
        ka3 = *(const uint4*)(kt + joff[3]);
      }
    }
    __syncthreads();
    QKPV(1, kb0, kb1, kb2, kb3);
  }
#undef QKPV

  // ---- epilogue -----------------------------------------------------------
  // row-sums: each lane owns query q=col; fetch sums for q=quad*4+r.
  lsum += __shfl_xor(lsum, 16);
  lsum += __shfl_xor(lsum, 32);
  float ls[4];
#pragma unroll
  for (int r = 0; r < 4; r++) ls[r] = __shfl(lsum, quad * 4 + r);

  // fused depthwise-3x3 conv + BN for this lane's 2 channels x 4 pixels.
  const int p0 = q0 + quad * 4;
  const int y  = p0 >> 5, x0 = p0 & 31;

#pragma unroll
  for (int dt = 0; dt < 2; dt++) {
    const int cl = dt * 16 + col;            // channel within head (0..31)
    const int ca = h * 32 + cl;              // global att channel (0..255)
    const u16* vrow = base + (size_t)(32 + cl) * NPIX;
    const float* w9 = wpos + ca * 9;
    const float cinv = rsqrtf(v_pos[ca] + EPS) * g_pos[ca];
    const float cadd = b_pos[ca] - m_pos[ca] * cinv;

    float cv0 = 0.f, cv1 = 0.f, cv2 = 0.f, cv3 = 0.f;
#pragma unroll
    for (int ky = 0; ky < 3; ky++) {
      const int yy = y + ky - 1;
      if (yy < 0 || yy > 31) continue;       // zero-pad rows
      const u16* rp = vrow + yy * 32 + x0;
      const float w0 = w9[ky * 3 + 0];
      const float w1 = w9[ky * 3 + 1];
      const float w2 = w9[ky * 3 + 2];
      const float tm = (x0 >= 1)      ? bf2f(rp[-1]) : 0.f;   // zero-pad cols
      const float t0 = bf2f(rp[0]);
      const float t1 = bf2f(rp[1]);
      const float t2 = bf2f(rp[2]);
      const float t3 = bf2f(rp[3]);
      const float t4 = (x0 + 4 <= 31) ? bf2f(rp[4]) : 0.f;
      cv0 += tm * w0 + t0 * w1 + t1 * w2;
      cv1 += t0 * w0 + t1 * w1 + t2 * w2;
      cv2 += t1 * w0 + t2 * w1 + t3 * w2;
      cv3 += t2 * w0 + t3 * w1 + t4 * w2;
    }

    const float o0v = o_acc[dt][0] * (1.f / ls[0]) + cv0 * cinv + cadd;
    const float o1v = o_acc[dt][1] * (1.f / ls[1]) + cv1 * cinv + cadd;
    const float o2v = o_acc[dt][2] * (1.f / ls[2]) + cv2 * cinv + cadd;
    const float o3v = o_acc[dt][3] * (1.f / ls[3]) + cv3 * cinv + cadd;

    // attT[b][pix][c] bf16
    const unsigned pa = cvtpk(o0v, o1v);
    const unsigned pb = cvtpk(o2v, o3v);
    const size_t ab = ((size_t)b * NPIX + p0) * 256 + ca;
    attT[ab      ] = (u16)pa;
    attT[ab + 256] = (u16)(pa >> 16);
    attT[ab + 512] = (u16)pb;
    attT[ab + 768] = (u16)(pb >> 16);
  }
}

// ---------------------------------------------------------------------------
extern "C" void kernel_launch(void* const* d_in, const int* in_sizes, int n_in,
                              void* d_out, int out_size, void* d_ws, size_t ws_size,
                              hipStream_t stream)
{
  (void)in_sizes; (void)n_in; (void)out_size;
  const float* x      = (const float*)d_in[0];
  const float* w_qkv  = (const float*)d_in[1];
  const float* g_qkv  = (const float*)d_in[2];
  const float* b_qkv  = (const float*)d_in[3];
  const float* m_qkv  = (const float*)d_in[4];
  const float* v_qkv  = (const float*)d_in[5];
  const float* w_pos  = (const float*)d_in[6];
  const float* g_pos  = (const float*)d_in[7];
  const float* b_pos  = (const float*)d_in[8];
  const float* m_pos  = (const float*)d_in[9];
  const float* v_pos  = (const float*)d_in[10];
  const float* w_proj = (const float*)d_in[11];
  const float* g_proj = (const float*)d_in[12];
  const float* b_proj = (const float*)d_in[13];
  const float* m_proj = (const float*)d_in[14];
  const float* v_proj = (const float*)d_in[15];

  // Buffer plan:
  //   qkv  bf16 (16,512,1024):        ws[0 .. 16.78MB)
  //   attT bf16 (16,1024,256):        ws[+16.78MB) or d_in[0] fallback
  //   ktr  bf16 (16,8,1024,16) K^T:   ws[+25.17MB) or d_out fallback
  //     (d_out hazard-free: attn reads ktr before gemm2 writes d_out)
  const size_t qkv_e  = (size_t)16 * 512 * NPIX;
  const size_t attT_e = (size_t)16 * NPIX * 256;
  const size_t ktr_e  = (size_t)16 * 8 * 1024 * 16;
  u16* qkv  = (u16*)d_ws;
  u16* attT;
  u16* ktr;
  if (ws_size >= (qkv_e + attT_e + ktr_e) * sizeof(u16)) {
    attT = (u16*)d_ws + qkv_e;
    ktr  = (u16*)d_ws + qkv_e + attT_e;
  } else if (ws_size >= (qkv_e + ktr_e) * sizeof(u16)) {
    ktr  = (u16*)d_ws + qkv_e;
    attT = (u16*)d_in[0];
  } else {
    ktr  = (u16*)d_out;
    attT = (u16*)d_in[0];
  }

  // 1. qkv = BN(x @ w_qkv^T); K channels diverted to ktr as K^T
  gemm_bn<false, false, true><<<dim3(16, 8, 16), 256, 0, stream>>>(
      x, w_qkv, g_qkv, b_qkv, m_qkv, v_qkv, qkv, nullptr, ktr, 256, 512);
  // 2. attT = attention(q,k,v) + BN(depthwise3x3(v))   [fused, bf16 pix-major]
  attn_mfma_kernel<<<dim3(16, 8, 16), 256, 0, stream>>>(
      qkv, ktr, attT, w_pos, g_pos, b_pos, m_pos, v_pos);
  // 3. out = BN(attT @ w_proj^T)    [f32 out, bf16 contiguous src]
  gemm_bn<true, true, false><<<dim3(16, 4, 16), 256, 0, stream>>>(
      attT, w_proj, g_proj, b_proj, m_proj, v_proj, nullptr,
      (float*)d_out, nullptr, 256, 256);
}

// Round 12
// 160.749 us; speedup vs baseline: 1.0345x; 1.0047x over previous
//
#include <hip/hip_runtime.h>

typedef short v8s __attribute__((ext_vector_type(8)));
typedef float v4f __attribute__((ext_vector_type(4)));
typedef unsigned short u16;

#define NPIX 1024
#define EPS 1e-5f

__device__ __forceinline__ float bf2f(u16 u){
  return __uint_as_float(((unsigned)u) << 16);
}
__device__ __forceinline__ u16 f2bf(float f){
  unsigned b = __float_as_uint(f);
  b += 0x7FFF + ((b >> 16) & 1);   // RNE
  return (u16)(b >> 16);
}
// pack two f32 -> two bf16 in one VALU op (RNE, same bits as f2bf)
__device__ __forceinline__ unsigned cvtpk(float lo, float hi){
  unsigned r;
  asm("v_cvt_pk_bf16_f32 %0, %1, %2" : "=v"(r) : "v"(lo), "v"(hi));
  return r;
}
// native v_exp_f32 (2^x), bypassing OCML's checked exp2f path
__device__ __forceinline__ float exp2n(float x){
#if __has_builtin(__builtin_amdgcn_exp2f)
  return __builtin_amdgcn_exp2f(x);
#else
  float r; asm("v_exp_f32 %0, %1" : "=v"(r) : "v"(x)); return r;
#endif
}
// Barrier that waits only LDS ops (lgkmcnt), NOT vmcnt: global prefetch
// loads stay in flight across the barrier (HIP __syncthreads drains
// vmcnt(0) -> defeats cross-barrier prefetch; this is the fix). The only
// cross-wave state at these barriers is LDS double-buffers, covered by
// lgkmcnt(0) + s_barrier. "memory" clobber orders all C++ LDS accesses.
__device__ __forceinline__ void bar_lds(){
  asm volatile("s_waitcnt lgkmcnt(0)\n\ts_barrier" ::: "memory");
}

// ---------------------------------------------------------------------------
// GEMM+BN (round-6 structure: K=32 steps, single-barrier dbuf) with
// counted-wait barriers: the next-tile register prefetch now genuinely
// overlaps compute (was drained by __syncthreads' vmcnt(0)).
// KTR (gemm1): wave 1 writes K^T[b][h][j][k] to ktr, skips qkv K store.
// grid: (16, Cout/64, B), block 256 (4 waves).
// ---------------------------------------------------------------------------
template<bool OUT_F32, bool BSRC, bool KTR>
__global__ __launch_bounds__(256) void gemm_bn(
    const void* __restrict__ srcv, const float* __restrict__ W,
    const float* __restrict__ gam, const float* __restrict__ bet,
    const float* __restrict__ mu,  const float* __restrict__ var,
    u16* __restrict__ bout, float* __restrict__ fout,
    u16* __restrict__ ktr, int Cin, int Cout)
{
  const int n0 = blockIdx.x * 64;   // pixel tile
  const int o0 = blockIdx.y * 64;   // out-channel tile
  const int b  = blockIdx.z;
  const int tid = threadIdx.x;
  const int w = tid >> 6, lane = tid & 63, col = lane & 15, quad = lane >> 4;

  const float* srcf = (const float*)srcv;
  const u16*   srcb = (const u16*)srcv;

  __shared__ u16 Wl[2][64 * 40];   // [o][k], stride 40 (80B rows, 16B-aligned)
  __shared__ u16 Sr[2][64 * 40];   // [pixel][k]

  // one BN coefficient set per lane (its single output channel)
  const int o = o0 + w * 16 + col;
  const float inv = rsqrtf(var[o] + EPS) * gam[o];
  const float add = bet[o] - mu[o] * inv;

  v4f acc[4];
#pragma unroll
  for (int i = 0; i < 4; i++) acc[i] = (v4f){0.f, 0.f, 0.f, 0.f};

  // staging assignments
  const int so = tid >> 2, sks = (tid & 3) * 8;   // W: 64 o-rows x 4 k-slots
  const int sp = tid & 63, skg = (tid >> 6) * 8;  // src: 64 pixels x 4 k-grps

  const float* wp = W + (size_t)(o0 + so) * Cin + sks;

  // prologue: tile 0 into regs
  float4 wa = ((const float4*)wp)[0];
  float4 wb = ((const float4*)wp)[1];
  float sv[8];
  v8s svb;
  if (BSRC) {
    svb = *(const v8s*)(&srcb[((size_t)b * NPIX + n0 + sp) * Cin + skg]);
  } else {
    const float* sb = srcf + ((size_t)b * Cin) * NPIX + n0 + sp;
#pragma unroll
    for (int i = 0; i < 8; i++) sv[i] = sb[(size_t)(skg + i) * NPIX];
  }

  const int nt = Cin >> 5;
  int cur = 0;
  for (int t = 0; t < nt; ++t) {
    {   // W tile -> LDS (contiguous k, no transpose)
      uint4 pk;
      pk.x = cvtpk(wa.x, wa.y);
      pk.y = cvtpk(wa.z, wa.w);
      pk.z = cvtpk(wb.x, wb.y);
      pk.w = cvtpk(wb.z, wb.w);
      *(uint4*)(&Wl[cur][so * 40 + sks]) = pk;
    }
    if (BSRC) {   // src tile: already bf16 [pixel][k] contiguous
      *(v8s*)(&Sr[cur][sp * 40 + skg]) = svb;
    } else {      // src tile: f32 transpose-gather -> bf16
      uint4 pk;
      pk.x = cvtpk(sv[0], sv[1]);
      pk.y = cvtpk(sv[2], sv[3]);
      pk.z = cvtpk(sv[4], sv[5]);
      pk.w = cvtpk(sv[6], sv[7]);
      *(uint4*)(&Sr[cur][sp * 40 + skg]) = pk;
    }
    if (t + 1 < nt) {   // issue next tile's loads (stay in flight past barrier)
      const float* wpn = wp + (t + 1) * 32;
      wa = ((const float4*)wpn)[0];
      wb = ((const float4*)wpn)[1];
      if (BSRC) {
        svb = *(const v8s*)(&srcb[((size_t)b * NPIX + n0 + sp) * Cin +
                                  (t + 1) * 32 + skg]);
      } else {
        const float* sbn = srcf + ((size_t)b * Cin) * NPIX + n0 + sp +
                           (size_t)((t + 1) * 32 + skg) * NPIX;
#pragma unroll
        for (int i = 0; i < 8; i++) sv[i] = sbn[(size_t)i * NPIX];
      }
    }
    bar_lds();

    v8s bfrag = *(const v8s*)(&Wl[cur][(w * 16 + col) * 40 + quad * 8]);
#pragma unroll
    for (int mt = 0; mt < 4; mt++) {
      v8s af = *(const v8s*)(&Sr[cur][(mt * 16 + col) * 40 + quad * 8]);
      acc[mt] = __builtin_amdgcn_mfma_f32_16x16x32_bf16(af, bfrag, acc[mt], 0, 0, 0);
    }
    cur ^= 1;
  }

  // epilogue: pixel = n0 + mt*16 + quad*4 + r (contiguous in r)
  if (KTR && w == 1) {
    // K channels: write K^T[(b,h)][j][k], j = pixel, k = col. Plain j order.
    const size_t ktb = (((size_t)b * 8 + blockIdx.y) * 1024 +
                       (size_t)blockIdx.x * 64) * 16 + col;
#pragma unroll
    for (int mt = 0; mt < 4; mt++) {
      float v0 = acc[mt][0] * inv + add;
      float v1 = acc[mt][1] * inv + add;
      float v2 = acc[mt][2] * inv + add;
      float v3 = acc[mt][3] * inv + add;
      unsigned pa = cvtpk(v0, v1);
      unsigned pb = cvtpk(v2, v3);
      const size_t rb = ktb + (size_t)(mt * 16 + quad * 4) * 16;
      ktr[rb     ] = (u16)pa;
      ktr[rb + 16] = (u16)(pa >> 16);
      ktr[rb + 32] = (u16)pb;
      ktr[rb + 48] = (u16)(pb >> 16);
    }
    return;
  }
  const size_t orow = (size_t)(b * Cout + o) * NPIX + n0 + quad * 4;
#pragma unroll
  for (int mt = 0; mt < 4; mt++) {
    float v0 = acc[mt][0] * inv + add;
    float v1 = acc[mt][1] * inv + add;
    float v2 = acc[mt][2] * inv + add;
    float v3 = acc[mt][3] * inv + add;
    if (OUT_F32) {
      *(float4*)(&fout[orow + mt * 16]) = make_float4(v0, v1, v2, v3);
    } else {
      uint2 pk;
      pk.x = cvtpk(v0, v1);
      pk.y = cvtpk(v2, v3);
      *(uint2*)(&bout[orow + mt * 16]) = pk;
    }
  }
}

// ---------------------------------------------------------------------------
// MFMA flash attention + FUSED depthwise-3x3+BN epilogue.
// Round-12: round-11 structure + counted-wait barriers (bar_lds) so the
// named-register K/V prefetch genuinely stays in flight across barriers
// (round-11's regression: __syncthreads vmcnt(0) drain made it synchronous).
// Also: P-fragment assembly de-arrayed (rule #20 scratch risk).
// grid: (16 batch, 8 heads, 16 q-tiles), block 256 (4 waves, 16 q/wave).
// ---------------------------------------------------------------------------
__global__ __launch_bounds__(256) void attn_mfma_kernel(
    const u16* __restrict__ qkv, const u16* __restrict__ ktr,
    u16* __restrict__ attT, const float* __restrict__ wpos,
    const float* __restrict__ g_pos, const float* __restrict__ b_pos,
    const float* __restrict__ m_pos, const float* __restrict__ v_pos)
{
  const int b = blockIdx.x, h = blockIdx.y, qt = blockIdx.z;  // XCD locality
  const int tid = threadIdx.x, w = tid >> 6, lane = tid & 63;
  const int col = lane & 15, quad = lane >> 4;
  const u16* base = qkv + (size_t)(b * 512 + h * 64) * NPIX;

  __shared__ u16 Vl[2][32 * 72];   // [d][j], stride 72

  const int q0 = qt * 64 + w * 16;

  // Q B-fragment (loop-invariant): B[n=q=col][k=quad*8+jj], k>=16 zero.
  // Scale = SCALE * log2(e) so scores feed exp2 directly.
  v8s qf = (v8s){0, 0, 0, 0, 0, 0, 0, 0};
  if (quad < 2) {
#pragma unroll
    for (int jj = 0; jj < 8; jj++) {
      int k = quad * 8 + jj;
      qf[jj] = (short)f2bf(bf2f(base[(size_t)k * NPIX + q0 + col])
                           * 0.36067376022224085f);
    }
  }

  // loop-invariant kf offsets: permuted row jt*16+col -> true j (inv-rho)
  int joff[4];
#pragma unroll
  for (int jt = 0; jt < 4; jt++) {
    const int row = jt * 16 + col;
    const int r4 = row >> 4;
    const int j = (r4 >> 1) * 32 + ((row >> 2) & 3) * 8 + (r4 & 1) * 4 + (row & 3);
    joff[jt] = j * 16 + quad * 8;
  }
  const u16* ktb = ktr + (size_t)(b * 8 + h) * 1024 * 16;

  float lsum = 0.f;
  v4f o_acc[2];
  o_acc[0] = (v4f){0, 0, 0, 0};
  o_acc[1] = (v4f){0, 0, 0, 0};

  const int vd = tid >> 3, vjs = (tid & 7) * 8;  // V staging

  // named double-buffered prefetch registers (no runtime-indexed arrays)
  uint4 ka0, ka1, ka2, ka3, kb0, kb1, kb2, kb3;
  ka0 = ka1 = ka2 = ka3 = kb0 = kb1 = kb2 = kb3 = make_uint4(0, 0, 0, 0);
  uint4 va, vb;

  // prologue: tile 0 -> regs A
  va = *(const uint4*)(base + (size_t)(32 + vd) * NPIX + vjs);
  if (quad < 2) {
    ka0 = *(const uint4*)(ktb + joff[0]);
    ka1 = *(const uint4*)(ktb + joff[1]);
    ka2 = *(const uint4*)(ktb + joff[2]);
    ka3 = *(const uint4*)(ktb + joff[3]);
  }

#define QK1(KF)                                                              \
  {                                                                          \
    v8s kf = *(const v8s*)&(KF);                                             \
    v4f z = (v4f){0, 0, 0, 0};                                               \
    v4f s = __builtin_amdgcn_mfma_f32_16x16x32_bf16(kf, qf, z, 0, 0, 0);     \
    float p0 = exp2n(s[0]);                                                  \
    float p1 = exp2n(s[1]);                                                  \
    float p2 = exp2n(s[2]);                                                  \
    float p3 = exp2n(s[3]);                                                  \
    lsum += (p0 + p1) + (p2 + p3);                                           \
    pka[jt] = cvtpk(p0, p1);                                                 \
    pkb[jt] = cvtpk(p2, p3);                                                 \
    jt++;                                                                    \
  }

#define QKPV(BUF, K0, K1, K2, K3)                                            \
  do {                                                                       \
    unsigned pka[4], pkb[4];                                                 \
    int jt = 0;                                                              \
    QK1(K0) QK1(K1) QK1(K2) QK1(K3)                                          \
    _Pragma("unroll")                                                        \
    for (int T = 0; T < 2; T++) {                                            \
      uint4 pfu = make_uint4(pka[2 * T], pkb[2 * T],                         \
                             pka[2 * T + 1], pkb[2 * T + 1]);                \
      v8s pf = *(v8s*)&pfu;                                                  \
      _Pragma("unroll")                                                      \
      for (int dt = 0; dt < 2; dt++) {                                       \
        v8s vf = *(const v8s*)(&Vl[BUF][(dt * 16 + col) * 72 +               \
                                        T * 32 + quad * 8]);                 \
        o_acc[dt] =                                                          \
            __builtin_amdgcn_mfma_f32_16x16x32_bf16(pf, vf, o_acc[dt], 0, 0, 0); \
      }                                                                      \
    }                                                                        \
  } while (0)

  for (int tt = 0; tt < 16; tt += 2) {
    // ---- even tile (regs A, buf 0); prefetch tile tt+1 into regs B
    *(uint4*)(&Vl[0][vd * 72 + vjs]) = va;
    {
      const int tn = tt + 1;
      vb = *(const uint4*)(base + (size_t)(32 + vd) * NPIX + tn * 64 + vjs);
      if (quad < 2) {
        const u16* kt = ktb + tn * 1024;
        kb0 = *(const uint4*)(kt + joff[0]);
        kb1 = *(const uint4*)(kt + joff[1]);
        kb2 = *(const uint4*)(kt + joff[2]);
        kb3 = *(const uint4*)(kt + joff[3]);
      }
    }
    bar_lds();   // LDS visibility only; prefetches stay in flight
    QKPV(0, ka0, ka1, ka2, ka3);

    // ---- odd tile (regs B, buf 1); prefetch tile tt+2 into regs A
    *(uint4*)(&Vl[1][vd * 72 + vjs]) = vb;
    if (tt + 2 < 16) {
      const int tn = tt + 2;
      va = *(const uint4*)(base + (size_t)(32 + vd) * NPIX + tn * 64 + vjs);
      if (quad < 2) {
        const u16* kt = ktb + tn * 1024;
        ka0 = *(const uint4*)(kt + joff[0]);
        ka1 = *(const uint4*)(kt + joff[1]);
        ka2 = *(const uint4*)(kt + joff[2]);
        ka3 = *(const uint4*)(kt + joff[3]);
      }
    }
    bar_lds();
    QKPV(1, kb0, kb1, kb2, kb3);
  }
#undef QKPV
#undef QK1

  // ---- epilogue -----------------------------------------------------------
  // row-sums: each lane owns query q=col; fetch sums for q=quad*4+r.
  lsum += __shfl_xor(lsum, 16);
  lsum += __shfl_xor(lsum, 32);
  float ls[4];
#pragma unroll
  for (int r = 0; r < 4; r++) ls[r] = __shfl(lsum, quad * 4 + r);

  // fused depthwise-3x3 conv + BN for this lane's 2 channels x 4 pixels.
  const int p0 = q0 + quad * 4;
  const int y  = p0 >> 5, x0 = p0 & 31;

#pragma unroll
  for (int dt = 0; dt < 2; dt++) {
    const int cl = dt * 16 + col;            // channel within head (0..31)
    const int ca = h * 32 + cl;              // global att channel (0..255)
    const u16* vrow = base + (size_t)(32 + cl) * NPIX;
    const float* w9 = wpos + ca * 9;
    const float cinv = rsqrtf(v_pos[ca] + EPS) * g_pos[ca];
    const float cadd = b_pos[ca] - m_pos[ca] * cinv;

    float cv0 = 0.f, cv1 = 0.f, cv2 = 0.f, cv3 = 0.f;
#pragma unroll
    for (int ky = 0; ky < 3; ky++) {
      const int yy = y + ky - 1;
      if (yy < 0 || yy > 31) continue;       // zero-pad rows
      const u16* rp = vrow + yy * 32 + x0;
      const float w0 = w9[ky * 3 + 0];
      const float w1 = w9[ky * 3 + 1];
      const float w2 = w9[ky * 3 + 2];
      const float tm = (x0 >= 1)      ? bf2f(rp[-1]) : 0.f;   // zero-pad cols
      const float t0 = bf2f(rp[0]);
      const float t1 = bf2f(rp[1]);
      const float t2 = bf2f(rp[2]);
      const float t3 = bf2f(rp[3]);
      const float t4 = (x0 + 4 <= 31) ? bf2f(rp[4]) : 0.f;
      cv0 += tm * w0 + t0 * w1 + t1 * w2;
      cv1 += t0 * w0 + t1 * w1 + t2 * w2;
      cv2 += t1 * w0 + t2 * w1 + t3 * w2;
      cv3 += t2 * w0 + t3 * w1 + t4 * w2;
    }

    const float o0v = o_acc[dt][0] * (1.f / ls[0]) + cv0 * cinv + cadd;
    const float o1v = o_acc[dt][1] * (1.f / ls[1]) + cv1 * cinv + cadd;
    const float o2v = o_acc[dt][2] * (1.f / ls[2]) + cv2 * cinv + cadd;
    const float o3v = o_acc[dt][3] * (1.f / ls[3]) + cv3 * cinv + cadd;

    // attT[b][pix][c] bf16
    const unsigned pa = cvtpk(o0v, o1v);
    const unsigned pb = cvtpk(o2v, o3v);
    const size_t ab = ((size_t)b * NPIX + p0) * 256 + ca;
    attT[ab      ] = (u16)pa;
    attT[ab + 256] = (u16)(pa >> 16);
    attT[ab + 512] = (u16)pb;
    attT[ab + 768] = (u16)(pb >> 16);
  }
}

// ---------------------------------------------------------------------------
extern "C" void kernel_launch(void* const* d_in, const int* in_sizes, int n_in,
                              void* d_out, int out_size, void* d_ws, size_t ws_size,
                              hipStream_t stream)
{
  (void)in_sizes; (void)n_in; (void)out_size;
  const float* x      = (const float*)d_in[0];
  const float* w_qkv  = (const float*)d_in[1];
  const float* g_qkv  = (const float*)d_in[2];
  const float* b_qkv  = (const float*)d_in[3];
  const float* m_qkv  = (const float*)d_in[4];
  const float* v_qkv  = (const float*)d_in[5];
  const float* w_pos  = (const float*)d_in[6];
  const float* g_pos  = (const float*)d_in[7];
  const float* b_pos  = (const float*)d_in[8];
  const float* m_pos  = (const float*)d_in[9];
  const float* v_pos  = (const float*)d_in[10];
  const float* w_proj = (const float*)d_in[11];
  const float* g_proj = (const float*)d_in[12];
  const float* b_proj = (const float*)d_in[13];
  const float* m_proj = (const float*)d_in[14];
  const float* v_proj = (const float*)d_in[15];

  // Buffer plan:
  //   qkv  bf16 (16,512,1024):        ws[0 .. 16.78MB)
  //   attT bf16 (16,1024,256):        ws[+16.78MB) or d_in[0] fallback
  //   ktr  bf16 (16,8,1024,16) K^T:   ws[+25.17MB) or d_out fallback
  const size_t qkv_e  = (size_t)16 * 512 * NPIX;
  const size_t attT_e = (size_t)16 * NPIX * 256;
  const size_t ktr_e  = (size_t)16 * 8 * 1024 * 16;
  u16* qkv  = (u16*)d_ws;
  u16* attT;
  u16* ktr;
  if (ws_size >= (qkv_e + attT_e + ktr_e) * sizeof(u16)) {
    attT = (u16*)d_ws + qkv_e;
    ktr  = (u16*)d_ws + qkv_e + attT_e;
  } else if (ws_size >= (qkv_e + ktr_e) * sizeof(u16)) {
    ktr  = (u16*)d_ws + qkv_e;
    attT = (u16*)d_in[0];
  } else {
    ktr  = (u16*)d_out;
    attT = (u16*)d_in[0];
  }

  // 1. qkv = BN(x @ w_qkv^T); K channels diverted to ktr as K^T
  gemm_bn<false, false, true><<<dim3(16, 8, 16), 256, 0, stream>>>(
      x, w_qkv, g_qkv, b_qkv, m_qkv, v_qkv, qkv, nullptr, ktr, 256, 512);
  // 2. attT = attention(q,k,v) + BN(depthwise3x3(v))   [fused, bf16 pix-major]
  attn_mfma_kernel<<<dim3(16, 8, 16), 256, 0, stream>>>(
      qkv, ktr, attT, w_pos, g_pos, b_pos, m_pos, v_pos);
  // 3. out = BN(attT @ w_proj^T)    [f32 out, bf16 contiguous src]
  gemm_bn<true, true, false><<<dim3(16, 4, 16), 256, 0, stream>>>(
      attT, w_proj, g_proj, b_proj, m_proj, v_proj, nullptr,
      (float*)d_out, nullptr, 256, 256);
}

// Round 14
// 158.762 us; speedup vs baseline: 1.0475x; 1.0125x over previous
//
#include <hip/hip_runtime.h>

typedef short v8s __attribute__((ext_vector_type(8)));
typedef float v4f __attribute__((ext_vector_type(4)));
typedef unsigned short u16;

#define NPIX 1024
#define EPS 1e-5f

__device__ __forceinline__ float bf2f(u16 u){
  return __uint_as_float(((unsigned)u) << 16);
}
__device__ __forceinline__ u16 f2bf(float f){
  unsigned b = __float_as_uint(f);
  b += 0x7FFF + ((b >> 16) & 1);   // RNE
  return (u16)(b >> 16);
}
// pack two f32 -> two bf16 in one VALU op (RNE, same bits as f2bf)
__device__ __forceinline__ unsigned cvtpk(float lo, float hi){
  unsigned r;
  asm("v_cvt_pk_bf16_f32 %0, %1, %2" : "=v"(r) : "v"(lo), "v"(hi));
  return r;
}
// native v_exp_f32 (2^x), bypassing OCML's checked exp2f path
__device__ __forceinline__ float exp2n(float x){
#if __has_builtin(__builtin_amdgcn_exp2f)
  return __builtin_amdgcn_exp2f(x);
#else
  float r; asm("v_exp_f32 %0, %1" : "=v"(r) : "v"(x)); return r;
#endif
}
// Barrier that waits only LDS ops (lgkmcnt), NOT vmcnt: global prefetch
// loads stay in flight across the barrier. Safe here because the only
// cross-wave state at these barriers is the LDS double-buffers (covered by
// lgkmcnt(0) + s_barrier); prefetched registers are wave-private, and the
// compiler inserts counted vmcnt waits at their consumption point.
__device__ __forceinline__ void bar_lds(){
  asm volatile("s_waitcnt lgkmcnt(0)\n\ts_barrier" ::: "memory");
}

// ---------------------------------------------------------------------------
// GEMM+BN (round-6 structure: K=32 steps, single-barrier dbuf) with
// counted-wait barriers (round-12, best-measured gemm config).
//   A-operand = src (m = pixel), staged [pixel][k].
//   B-operand = W   (n = o-chan), [o][k] row-major -> contiguous-k b128.
// BSRC=false: src f32 [b][c][pix] transpose-gather. BSRC=true: bf16
// [b][pix][c] contiguous 16B load.
// grid: (16, Cout/64, B), block 256 (4 waves).
// ---------------------------------------------------------------------------
template<bool OUT_F32, bool BSRC>
__global__ __launch_bounds__(256) void gemm_bn(
    const void* __restrict__ srcv, const float* __restrict__ W,
    const float* __restrict__ gam, const float* __restrict__ bet,
    const float* __restrict__ mu,  const float* __restrict__ var,
    u16* __restrict__ bout, float* __restrict__ fout, int Cin, int Cout)
{
  const int n0 = blockIdx.x * 64;   // pixel tile
  const int o0 = blockIdx.y * 64;   // out-channel tile
  const int b  = blockIdx.z;
  const int tid = threadIdx.x;
  const int w = tid >> 6, lane = tid & 63, col = lane & 15, quad = lane >> 4;

  const float* srcf = (const float*)srcv;
  const u16*   srcb = (const u16*)srcv;

  __shared__ u16 Wl[2][64 * 40];   // [o][k], stride 40 (80B rows, 16B-aligned)
  __shared__ u16 Sr[2][64 * 40];   // [pixel][k]

  // one BN coefficient set per lane (its single output channel)
  const int o = o0 + w * 16 + col;
  const float inv = rsqrtf(var[o] + EPS) * gam[o];
  const float add = bet[o] - mu[o] * inv;

  v4f acc[4];
#pragma unroll
  for (int i = 0; i < 4; i++) acc[i] = (v4f){0.f, 0.f, 0.f, 0.f};

  // staging assignments
  const int so = tid >> 2, sks = (tid & 3) * 8;   // W: 64 o-rows x 4 k-slots
  const int sp = tid & 63, skg = (tid >> 6) * 8;  // src: 64 pixels x 4 k-grps

  const float* wp = W + (size_t)(o0 + so) * Cin + sks;

  // prologue: tile 0 into regs
  float4 wa = ((const float4*)wp)[0];
  float4 wb = ((const float4*)wp)[1];
  float sv[8];
  v8s svb;
  if (BSRC) {
    svb = *(const v8s*)(&srcb[((size_t)b * NPIX + n0 + sp) * Cin + skg]);
  } else {
    const float* sb = srcf + ((size_t)b * Cin) * NPIX + n0 + sp;
#pragma unroll
    for (int i = 0; i < 8; i++) sv[i] = sb[(size_t)(skg + i) * NPIX];
  }

  const int nt = Cin >> 5;
  int cur = 0;
  for (int t = 0; t < nt; ++t) {
    {   // W tile -> LDS (contiguous k, no transpose)
      uint4 pk;
      pk.x = cvtpk(wa.x, wa.y);
      pk.y = cvtpk(wa.z, wa.w);
      pk.z = cvtpk(wb.x, wb.y);
      pk.w = cvtpk(wb.z, wb.w);
      *(uint4*)(&Wl[cur][so * 40 + sks]) = pk;
    }
    if (BSRC) {   // src tile: already bf16 [pixel][k] contiguous
      *(v8s*)(&Sr[cur][sp * 40 + skg]) = svb;
    } else {      // src tile: f32 transpose-gather -> bf16
      uint4 pk;
      pk.x = cvtpk(sv[0], sv[1]);
      pk.y = cvtpk(sv[2], sv[3]);
      pk.z = cvtpk(sv[4], sv[5]);
      pk.w = cvtpk(sv[6], sv[7]);
      *(uint4*)(&Sr[cur][sp * 40 + skg]) = pk;
    }
    if (t + 1 < nt) {   // issue next tile's loads (stay in flight past barrier)
      const float* wpn = wp + (t + 1) * 32;
      wa = ((const float4*)wpn)[0];
      wb = ((const float4*)wpn)[1];
      if (BSRC) {
        svb = *(const v8s*)(&srcb[((size_t)b * NPIX + n0 + sp) * Cin +
                                  (t + 1) * 32 + skg]);
      } else {
        const float* sbn = srcf + ((size_t)b * Cin) * NPIX + n0 + sp +
                           (size_t)((t + 1) * 32 + skg) * NPIX;
#pragma unroll
        for (int i = 0; i < 8; i++) sv[i] = sbn[(size_t)i * NPIX];
      }
    }
    bar_lds();

    v8s bfrag = *(const v8s*)(&Wl[cur][(w * 16 + col) * 40 + quad * 8]);
#pragma unroll
    for (int mt = 0; mt < 4; mt++) {
      v8s af = *(const v8s*)(&Sr[cur][(mt * 16 + col) * 40 + quad * 8]);
      acc[mt] = __builtin_amdgcn_mfma_f32_16x16x32_bf16(af, bfrag, acc[mt], 0, 0, 0);
    }
    cur ^= 1;
  }

  // epilogue: pixel = n0 + mt*16 + quad*4 + r (contiguous in r)
  const size_t orow = (size_t)(b * Cout + o) * NPIX + n0 + quad * 4;
#pragma unroll
  for (int mt = 0; mt < 4; mt++) {
    float v0 = acc[mt][0] * inv + add;
    float v1 = acc[mt][1] * inv + add;
    float v2 = acc[mt][2] * inv + add;
    float v3 = acc[mt][3] * inv + add;
    if (OUT_F32) {
      *(float4*)(&fout[orow + mt * 16]) = make_float4(v0, v1, v2, v3);
    } else {
      uint2 pk;
      pk.x = cvtpk(v0, v1);
      pk.y = cvtpk(v2, v3);
      *(uint2*)(&bout[orow + mt * 16]) = pk;
    }
  }
}

// ---------------------------------------------------------------------------
// MFMA flash attention + FUSED depthwise-3x3+BN epilogue.
// Round-14 = round-13 resubmission (infra timeout, never ran):
// round-10 body (best measured: 45.4us, 56% occ, 3.67M conflicts) with
// bar_lds barriers. Mechanism for bar_lds HERE (unlike round-12's global-K
// kernel): K/V prefetch regs are consumed one barrier AFTER issue (at the
// next tile's LDS store), so removing the vmcnt(0) drain lets the loads
// overlap the current tile's full compute phase.
//  - K-row permutation rho(j) makes each lane's 16 QK^T outputs exactly its
//    PV A-fragment -> P stays in registers (no P LDS round-trip).
//  - XCD locality: b=blockIdx.x, qt=blockIdx.z.
// grid: (16 batch, 8 heads, 16 q-tiles), block 256 (4 waves, 16 q/wave).
// ---------------------------------------------------------------------------
__global__ __launch_bounds__(256) void attn_mfma_kernel(
    const u16* __restrict__ qkv, u16* __restrict__ attT,
    const float* __restrict__ wpos,
    const float* __restrict__ g_pos, const float* __restrict__ b_pos,
    const float* __restrict__ m_pos, const float* __restrict__ v_pos)
{
  const int b = blockIdx.x, h = blockIdx.y, qt = blockIdx.z;  // XCD locality
  const int tid = threadIdx.x, w = tid >> 6, lane = tid & 63;
  const int col = lane & 15, quad = lane >> 4;
  const u16* base = qkv + (size_t)(b * 512 + h * 64) * NPIX;

  __shared__ u16 Kt[2][64 * 24];   // [rho(j)][k] permuted-transposed, stride 24
  __shared__ u16 Vl[2][32 * 72];   // [d][j], stride 72

  const int q0 = qt * 64 + w * 16;

  // Q B-fragment (loop-invariant): B[n=q=col][k=quad*8+jj], k>=16 zero.
  // Scale = SCALE * log2(e) so scores feed exp2 directly.
  v8s qf = (v8s){0, 0, 0, 0, 0, 0, 0, 0};
  if (quad < 2) {
#pragma unroll
    for (int jj = 0; jj < 8; jj++) {
      int k = quad * 8 + jj;
      qf[jj] = (short)f2bf(bf2f(base[(size_t)k * NPIX + q0 + col])
                           * 0.36067376022224085f);
    }
  }

  float lsum = 0.f;
  v4f o_acc[2];
  o_acc[0] = (v4f){0, 0, 0, 0};
  o_acc[1] = (v4f){0, 0, 0, 0};

  const int kk4 = w * 4;                         // wave w stages k rows w*4..+3
  const int vd = tid >> 3, vjs = (tid & 7) * 8;  // V staging

  // permuted Kt destination row for the key this lane stages (j = lane)
  const int rho = ((2 * (lane >> 5) + ((lane & 7) >> 2)) << 4)
                  + (((lane >> 3) & 3) << 2) + (lane & 3);

  // prologue: tile 0 into regs
  ushort4 kr;
  kr.x = base[(size_t)(16 + kk4 + 0) * NPIX + lane];
  kr.y = base[(size_t)(16 + kk4 + 1) * NPIX + lane];
  kr.z = base[(size_t)(16 + kk4 + 2) * NPIX + lane];
  kr.w = base[(size_t)(16 + kk4 + 3) * NPIX + lane];
  uint4 vr = *(const uint4*)(base + (size_t)(32 + vd) * NPIX + vjs);

  int cur = 0;
  for (int t = 0; t < 16; ++t) {
    *(ushort4*)(&Kt[cur][rho * 24 + kk4]) = kr;    // key j=lane -> row rho(j)
    *(uint4*)(&Vl[cur][vd * 72 + vjs]) = vr;       // V: Vl[d][j], true order
    if (t < 15) {   // issue next tile's loads (stay in flight past barrier)
      const int j0n = (t + 1) * 64;
      kr.x = base[(size_t)(16 + kk4 + 0) * NPIX + j0n + lane];
      kr.y = base[(size_t)(16 + kk4 + 1) * NPIX + j0n + lane];
      kr.z = base[(size_t)(16 + kk4 + 2) * NPIX + j0n + lane];
      kr.w = base[(size_t)(16 + kk4 + 3) * NPIX + j0n + lane];
      vr = *(const uint4*)(base + (size_t)(32 + vd) * NPIX + j0n + vjs);
    }
    bar_lds();   // LDS visibility only; prefetch loads stay in flight

    // scores + exp2 + packed P kept IN REGISTERS.
    // s = mfma(K,Q): lane (quad,col) gets P[key rho^-1(jt*16+quad*4+r)][q=col]
    // = by construction the keys {quad*8+jj, 32+quad*8+jj} its PV needs.
    unsigned pka[4], pkb[4];
#pragma unroll
    for (int jt = 0; jt < 4; jt++) {
      v8s kf = (v8s){0, 0, 0, 0, 0, 0, 0, 0};
      if (quad < 2)
        kf = *(const v8s*)(&Kt[cur][(jt * 16 + col) * 24 + quad * 8]);
      v4f z = (v4f){0, 0, 0, 0};
      v4f s = __builtin_amdgcn_mfma_f32_16x16x32_bf16(kf, qf, z, 0, 0, 0);
      float p0 = exp2n(s[0]);
      float p1 = exp2n(s[1]);
      float p2 = exp2n(s[2]);
      float p3 = exp2n(s[3]);
      lsum += (p0 + p1) + (p2 + p3);
      pka[jt] = cvtpk(p0, p1);
      pkb[jt] = cvtpk(p2, p3);
    }

    // PV: D[m=query][n=d]; pf assembled from this lane's own registers.
#pragma unroll
    for (int T = 0; T < 2; T++) {
      uint4 pfu = make_uint4(pka[2 * T], pkb[2 * T],
                             pka[2 * T + 1], pkb[2 * T + 1]);
      v8s pf = *(v8s*)&pfu;
#pragma unroll
      for (int dt = 0; dt < 2; dt++) {
        v8s vf = *(const v8s*)(&Vl[cur][(dt * 16 + col) * 72 + T * 32 + quad * 8]);
        o_acc[dt] = __builtin_amdgcn_mfma_f32_16x16x32_bf16(pf, vf, o_acc[dt], 0, 0, 0);
      }
    }
    cur ^= 1;
  }

  // ---- epilogue -----------------------------------------------------------
  // row-sums: each lane owns query q=col; fetch sums for q=quad*4+r.
  lsum += __shfl_xor(lsum, 16);
  lsum += __shfl_xor(lsum, 32);
  float ls[4];
#pragma unroll
  for (int r = 0; r < 4; r++) ls[r] = __shfl(lsum, quad * 4 + r);

  // fused depthwise-3x3 conv + BN for this lane's 2 channels x 4 pixels.
  const int p0 = q0 + quad * 4;
  const int y  = p0 >> 5, x0 = p0 & 31;

#pragma unroll
  for (int dt = 0; dt < 2; dt++) {
    const int cl = dt * 16 + col;            // channel within head (0..31)
    const int ca = h * 32 + cl;              // global att channel (0..255)
    const u16* vrow = base + (size_t)(32 + cl) * NPIX;
    const float* w9 = wpos + ca * 9;
    const float cinv = rsqrtf(v_pos[ca] + EPS) * g_pos[ca];
    const float cadd = b_pos[ca] - m_pos[ca] * cinv;

    float cv0 = 0.f, cv1 = 0.f, cv2 = 0.f, cv3 = 0.f;
#pragma unroll
    for (int ky = 0; ky < 3; ky++) {
      const int yy = y + ky - 1;
      if (yy < 0 || yy > 31) continue;       // zero-pad rows
      const u16* rp = vrow + yy * 32 + x0;
      const float w0 = w9[ky * 3 + 0];
      const float w1 = w9[ky * 3 + 1];
      const float w2 = w9[ky * 3 + 2];
      const float tm = (x0 >= 1)      ? bf2f(rp[-1]) : 0.f;   // zero-pad cols
      const float t0 = bf2f(rp[0]);
      const float t1 = bf2f(rp[1]);
      const float t2 = bf2f(rp[2]);
      const float t3 = bf2f(rp[3]);
      const float t4 = (x0 + 4 <= 31) ? bf2f(rp[4]) : 0.f;
      cv0 += tm * w0 + t0 * w1 + t1 * w2;
      cv1 += t0 * w0 + t1 * w1 + t2 * w2;
      cv2 += t1 * w0 + t2 * w1 + t3 * w2;
      cv3 += t2 * w0 + t3 * w1 + t4 * w2;
    }

    const float o0v = o_acc[dt][0] * (1.f / ls[0]) + cv0 * cinv + cadd;
    const float o1v = o_acc[dt][1] * (1.f / ls[1]) + cv1 * cinv + cadd;
    const float o2v = o_acc[dt][2] * (1.f / ls[2]) + cv2 * cinv + cadd;
    const float o3v = o_acc[dt][3] * (1.f / ls[3]) + cv3 * cinv + cadd;

    // attT[b][pix][c] bf16
    const unsigned pa = cvtpk(o0v, o1v);
    const unsigned pb = cvtpk(o2v, o3v);
    const size_t ab = ((size_t)b * NPIX + p0) * 256 + ca;
    attT[ab      ] = (u16)pa;
    attT[ab + 256] = (u16)(pa >> 16);
    attT[ab + 512] = (u16)pb;
    attT[ab + 768] = (u16)(pb >> 16);
  }
}

// ---------------------------------------------------------------------------
extern "C" void kernel_launch(void* const* d_in, const int* in_sizes, int n_in,
                              void* d_out, int out_size, void* d_ws, size_t ws_size,
                              hipStream_t stream)
{
  (void)in_sizes; (void)n_in; (void)out_size;
  const float* x      = (const float*)d_in[0];
  const float* w_qkv  = (const float*)d_in[1];
  const float* g_qkv  = (const float*)d_in[2];
  const float* b_qkv  = (const float*)d_in[3];
  const float* m_qkv  = (const float*)d_in[4];
  const float* v_qkv  = (const float*)d_in[5];
  const float* w_pos  = (const float*)d_in[6];
  const float* g_pos  = (const float*)d_in[7];
  const float* b_pos  = (const float*)d_in[8];
  const float* m_pos  = (const float*)d_in[9];
  const float* v_pos  = (const float*)d_in[10];
  const float* w_proj = (const float*)d_in[11];
  const float* g_proj = (const float*)d_in[12];
  const float* b_proj = (const float*)d_in[13];
  const float* m_proj = (const float*)d_in[14];
  const float* v_proj = (const float*)d_in[15];

  // Buffer plan:
  //   qkv  bf16 (16,512,1024):        ws[0 .. 16.78MB)
  //   attT bf16 (16,1024,256):        ws[+16.78MB) or d_in[0] fallback
  const size_t qkv_e  = (size_t)16 * 512 * NPIX;
  const size_t attT_e = (size_t)16 * NPIX * 256;
  u16* qkv  = (u16*)d_ws;
  u16* attT = (ws_size >= (qkv_e + attT_e) * sizeof(u16))
                ? (u16*)d_ws + qkv_e
                : (u16*)d_in[0];

  // 1. qkv = BN(x @ w_qkv^T)        [bf16 out, f32 gather src]
  gemm_bn<false, false><<<dim3(16, 8, 16), 256, 0, stream>>>(
      x, w_qkv, g_qkv, b_qkv, m_qkv, v_qkv, qkv, nullptr, 256, 512);
  // 2. attT = attention(q,k,v) + BN(depthwise3x3(v))   [fused, bf16 pix-major]
  attn_mfma_kernel<<<dim3(16, 8, 16), 256, 0, stream>>>(
      qkv, attT, w_pos, g_pos, b_pos, m_pos, v_pos);
  // 3. out = BN(attT @ w_proj^T)    [f32 out, bf16 contiguous src]
  gemm_bn<true, true><<<dim3(16, 4, 16), 256, 0, stream>>>(
      attT, w_proj, g_proj, b_proj, m_proj, v_proj, nullptr,
      (float*)d_out, 256, 256);
}